// Round 1
// baseline (271.099 us; speedup 1.0000x reference)
//
#include <hip/hip_runtime.h>
#include <hip/hip_bf16.h>
#include <float.h>
#include <stdint.h>

#define NPTS 8192
#define NSEG 4
#define SEG  2048
#define CF   16
#define HID1 64
#define HID2 128
#define KMAX 64
#define R2   0.49f
#define CAND_CAP 1024

__device__ __forceinline__ uint32_t f2ord(float f) {
    uint32_t u = __float_as_uint(f);
    return (u & 0x80000000u) ? ~u : (u | 0x80000000u);
}

__global__ __launch_bounds__(256, 2) void pointconv_kernel(
    const float* __restrict__ x, const float* __restrict__ pos,
    const int* __restrict__ batch,
    const float* __restrict__ W1, const float* __restrict__ b1,
    const float* __restrict__ W2, const float* __restrict__ b2,
    float* __restrict__ out)
{
    __shared__ unsigned long long s_key[CAND_CAP];  // 8192 B
    __shared__ float s_W1[19][HID1];                // 4864 B
    __shared__ float s_b1[HID1];
    __shared__ float s_W2[HID1][HID2];              // 32768 B
    __shared__ float s_b2[HID2];
    __shared__ float s_feat[KMAX][20];              // 5120 B
    __shared__ float s_h1T[HID1][68];               // 17408 B (stride 68: 16B-aligned rows, bank-spread)
    __shared__ float s_red[16][132];                // 8448 B
    __shared__ int   s_nbr[KMAX];
    __shared__ int   s_cnt;

    const int tid = threadIdx.x;
    const int i   = blockIdx.x;

    // ---- stage weights into LDS ----
    for (int t = tid; t < 19 * HID1; t += 256) s_W1[t >> 6][t & 63] = W1[t];
    for (int t = tid; t < HID1; t += 256)      s_b1[t] = b1[t];
    for (int t = tid; t < HID1 * HID2; t += 256) s_W2[t >> 7][t & 127] = W2[t];
    for (int t = tid; t < HID2; t += 256)      s_b2[t] = b2[t];
    if (tid == 0) s_cnt = 0;

    const int   seg0 = batch[i] * SEG;
    const float pix = pos[3 * i + 0], piy = pos[3 * i + 1], piz = pos[3 * i + 2];
    // sq exactly like np: per-op rounded x*x + y*y + z*z (no fma contraction)
    const float sqi = __fadd_rn(__fadd_rn(__fmul_rn(pix, pix), __fmul_rn(piy, piy)),
                                __fmul_rn(piz, piz));

    __syncthreads();

    // ---- candidate scan: d2 = (sq_i + sq_j) - 2*dot, matching reference formula ----
    for (int jj = tid; jj < SEG; jj += 256) {
        const int j = seg0 + jj;
        const float pjx = pos[3 * j + 0], pjy = pos[3 * j + 1], pjz = pos[3 * j + 2];
        const float sqj = __fadd_rn(__fadd_rn(__fmul_rn(pjx, pjx), __fmul_rn(pjy, pjy)),
                                    __fmul_rn(pjz, pjz));
        const float dot = fmaf(piz, pjz, fmaf(piy, pjy, __fmul_rn(pix, pjx)));
        const float d2 = __fsub_rn(__fadd_rn(sqi, sqj), __fmul_rn(2.0f, dot));
        if (d2 <= R2) {
            int p = atomicAdd(&s_cnt, 1);
            if (p < CAND_CAP)
                s_key[p] = ((unsigned long long)f2ord(d2) << 32) | (unsigned)j;
        }
    }
    __syncthreads();

    int cnt = s_cnt; if (cnt > CAND_CAP) cnt = CAND_CAP;
    const int m = cnt < KMAX ? cnt : KMAX;

    if (cnt > KMAX) {
        // bitonic sort of next-pow2-padded keys: exact (d2, j) lexicographic top-K
        int np2 = 1; while (np2 < cnt) np2 <<= 1;
        for (int e = cnt + tid; e < np2; e += 256) s_key[e] = ~0ULL;
        __syncthreads();
        for (int k = 2; k <= np2; k <<= 1) {
            for (int j = k >> 1; j > 0; j >>= 1) {
                for (int e = tid; e < np2; e += 256) {
                    const int l = e ^ j;
                    if (l > e) {
                        const unsigned long long a = s_key[e], b = s_key[l];
                        const bool asc = ((e & k) == 0);
                        if ((a > b) == asc) { s_key[e] = b; s_key[l] = a; }
                    }
                }
                __syncthreads();
            }
        }
    }
    if (tid < KMAX) s_nbr[tid] = (tid < m) ? (int)(s_key[tid] & 0xffffffffu) : -1;
    __syncthreads();

    // ---- gather features: [x_j (16), pos_j - pos_i (3)] ----
    for (int t = tid; t < m * 19; t += 256) {
        const int n = t / 19, c = t - n * 19;
        const int j = s_nbr[n];
        float v;
        if (c < 16) v = x[j * CF + c];
        else {
            const float pj = pos[3 * j + (c - 16)];
            const float pi = (c == 16) ? pix : ((c == 17) ? piy : piz);
            v = pj - pi;
        }
        s_feat[n][c] = v;
    }
    __syncthreads();

    // ---- h1 = relu(feat @ W1 + b1), stored transposed h1T[k][n] ----
    {
        const int lane = tid & 63, wid = tid >> 6;
        #pragma unroll
        for (int p = 0; p < 16; ++p) {
            const int n = p * 4 + wid;
            float acc = 0.0f;
            if (n < m) {
                acc = s_b1[lane];
                #pragma unroll
                for (int c = 0; c < 19; ++c)
                    acc = fmaf(s_feat[n][c], s_W1[c][lane], acc);
                acc = fmaxf(acc, 0.0f);
            }
            s_h1T[lane][n] = acc;
        }
    }
    __syncthreads();

    // ---- h2 = h1 @ W2 + b2, 4n x 8c register tiles, partial max over n ----
    {
        const int nb = tid & 15, cb = tid >> 4;
        const int n0 = nb * 4, c0 = cb * 8;
        float acc[4][8];
        #pragma unroll
        for (int nn = 0; nn < 4; ++nn)
            #pragma unroll
            for (int cc = 0; cc < 8; ++cc) acc[nn][cc] = s_b2[c0 + cc];

        #pragma unroll 4
        for (int k = 0; k < HID1; ++k) {
            const float4 h  = *(const float4*)&s_h1T[k][n0];
            const float4 w0 = *(const float4*)&s_W2[k][c0];
            const float4 w1 = *(const float4*)&s_W2[k][c0 + 4];
            const float hv[4] = { h.x, h.y, h.z, h.w };
            const float wv[8] = { w0.x, w0.y, w0.z, w0.w, w1.x, w1.y, w1.z, w1.w };
            #pragma unroll
            for (int nn = 0; nn < 4; ++nn)
                #pragma unroll
                for (int cc = 0; cc < 8; ++cc)
                    acc[nn][cc] = fmaf(hv[nn], wv[cc], acc[nn][cc]);
        }

        #pragma unroll
        for (int cc = 0; cc < 8; ++cc) {
            float v = -FLT_MAX;
            #pragma unroll
            for (int nn = 0; nn < 4; ++nn)
                if (n0 + nn < m) v = fmaxf(v, acc[nn][cc]);
            s_red[nb][c0 + cc] = v;
        }
    }
    __syncthreads();

    // ---- final max over the 16 n-blocks, then relu, write ----
    for (int c = tid; c < HID2; c += 256) {
        float v = -FLT_MAX;
        #pragma unroll
        for (int nbq = 0; nbq < 16; ++nbq) v = fmaxf(v, s_red[nbq][c]);
        out[(size_t)i * HID2 + c] = fmaxf(v, 0.0f);
    }
}

// echo pos (float) and batch (as float) into the tail of d_out
__global__ void echo_kernel(const float* __restrict__ pos,
                            const int* __restrict__ batch,
                            float* __restrict__ out)
{
    const int t = blockIdx.x * 256 + threadIdx.x;
    if (t < NPTS * 3) out[NPTS * HID2 + t] = pos[t];
    if (t < NPTS)     out[NPTS * HID2 + NPTS * 3 + t] = (float)batch[t];
}

extern "C" void kernel_launch(void* const* d_in, const int* in_sizes, int n_in,
                              void* d_out, int out_size, void* d_ws, size_t ws_size,
                              hipStream_t stream) {
    const float* x     = (const float*)d_in[0];
    const float* pos   = (const float*)d_in[1];
    const int*   batch = (const int*)d_in[2];
    const float* W1    = (const float*)d_in[3];
    const float* b1    = (const float*)d_in[4];
    const float* W2    = (const float*)d_in[5];
    const float* b2    = (const float*)d_in[6];
    float* out = (float*)d_out;

    hipLaunchKernelGGL(pointconv_kernel, dim3(NPTS), dim3(256), 0, stream,
                       x, pos, batch, W1, b1, W2, b2, out);
    hipLaunchKernelGGL(echo_kernel, dim3((NPTS * 3 + 255) / 256), dim3(256), 0, stream,
                       pos, batch, out);
}

// Round 3
// 171.982 us; speedup vs baseline: 1.5763x; 1.5763x over previous
//
#include <hip/hip_runtime.h>
#include <hip/hip_bf16.h>
#include <float.h>
#include <stdint.h>

#define NPTS 8192
#define SEG  2048
#define CF   16
#define HID1 64
#define HID2 128
#define KMAX 64
#define R2   0.49f
#define CAND_CAP 1024
#define H1S  68   // h1T row stride (floats): 16B-aligned rows

typedef unsigned long long ULL;

__device__ __forceinline__ uint32_t f2ord(float f) {
    uint32_t u = __float_as_uint(f);
    return (u & 0x80000000u) ? ~u : (u | 0x80000000u);
}

// ---- prep: A = x@W1[:16] + pos@W1[16:19] + b1 ; C = pos@W1[16:19] ; sq ; echo ----
__global__ __launch_bounds__(256) void prep_kernel(
    const float* __restrict__ x, const float* __restrict__ pos,
    const int* __restrict__ batch,
    const float* __restrict__ W1, const float* __restrict__ b1,
    float* __restrict__ A, float* __restrict__ C, float* __restrict__ sq,
    float* __restrict__ out)
{
    const int t = blockIdx.x * 256 + threadIdx.x;   // t < NPTS*64
    const int i = t >> 6, k = t & 63;

    const float px = pos[3 * i + 0], py = pos[3 * i + 1], pz = pos[3 * i + 2];
    float c = __fmul_rn(px, W1[16 * HID1 + k]);
    c = fmaf(py, W1[17 * HID1 + k], c);
    c = fmaf(pz, W1[18 * HID1 + k], c);

    float a = b1[k];
    #pragma unroll
    for (int cc = 0; cc < CF; ++cc)
        a = fmaf(x[i * CF + cc], W1[cc * HID1 + k], a);
    a += c;

    A[t] = a;
    C[t] = c;

    if (k == 0) {
        // exact np formula for sq: per-op rounded x*x + y*y + z*z
        sq[i] = __fadd_rn(__fadd_rn(__fmul_rn(px, px), __fmul_rn(py, py)),
                          __fmul_rn(pz, pz));
    }
    if (k < 3) out[NPTS * HID2 + 3 * i + k] = pos[3 * i + k];
    if (k == 3) out[NPTS * HID2 + NPTS * 3 + i] = (float)batch[i];
}

// ---- fused: radius scan -> exact top-K -> h1T = relu(A[j]-C[i]) -> h2 -> max ----
__global__ __launch_bounds__(256, 4) void pointconv_kernel(
    const float* __restrict__ pos, const int* __restrict__ batch,
    const float* __restrict__ W2, const float* __restrict__ b2,
    const float* __restrict__ A, const float* __restrict__ C,
    const float* __restrict__ sq, float* __restrict__ out)
{
    __shared__ ULL   s_key[CAND_CAP];     // 8 KB
    __shared__ float s_h1T[HID1][H1S];    // 17.4 KB
    __shared__ float s_b2[HID2];
    __shared__ int   s_nbr[KMAX];
    __shared__ int   s_cnt;

    const int tid = threadIdx.x;
    const int i   = blockIdx.x;

    if (tid < HID2) s_b2[tid] = b2[tid];
    if (tid == 0) s_cnt = 0;

    const int   seg0 = batch[i] * SEG;
    const float pix = pos[3 * i + 0], piy = pos[3 * i + 1], piz = pos[3 * i + 2];
    const float sqi = sq[i];
    __syncthreads();

    // candidate scan, exact reference arithmetic: d2 = (sq_i+sq_j) - 2*dot
    for (int jj = tid; jj < SEG; jj += 256) {
        const int j = seg0 + jj;
        const float pjx = pos[3 * j + 0], pjy = pos[3 * j + 1], pjz = pos[3 * j + 2];
        const float dot = fmaf(piz, pjz, fmaf(piy, pjy, __fmul_rn(pix, pjx)));
        const float d2  = __fsub_rn(__fadd_rn(sqi, sq[j]), __fmul_rn(2.0f, dot));
        if (d2 <= R2) {
            int p = atomicAdd(&s_cnt, 1);
            if (p < CAND_CAP)
                s_key[p] = ((ULL)f2ord(d2) << 32) | (unsigned)j;
        }
    }
    __syncthreads();

    int cnt = s_cnt; if (cnt > CAND_CAP) cnt = CAND_CAP;
    const int m = cnt < KMAX ? cnt : KMAX;

    if (cnt > KMAX) {
        int np2 = 1; while (np2 < cnt) np2 <<= 1;
        for (int e = cnt + tid; e < np2; e += 256) s_key[e] = ~0ULL;
        __syncthreads();
        for (int k = 2; k <= np2; k <<= 1) {
            for (int j = k >> 1; j > 0; j >>= 1) {
                for (int e = tid; e < np2; e += 256) {
                    const int l = e ^ j;
                    if (l > e) {
                        const ULL a = s_key[e], b = s_key[l];
                        const bool asc = ((e & k) == 0);
                        if ((a > b) == asc) { s_key[e] = b; s_key[l] = a; }
                    }
                }
                __syncthreads();
            }
        }
    }
    if (tid < KMAX) s_nbr[tid] = (tid < m) ? (int)(s_key[tid] & 0xffffffffu) : -1;
    __syncthreads();

    // h1T[k][n] = relu(A[j_n][k] - C[i][k]); zeros for padded rows
    {
        const int k = tid & 63, w = tid >> 6;
        const float cik = C[i * HID1 + k];
        #pragma unroll
        for (int p = 0; p < 16; ++p) {
            const int n = p * 4 + w;
            float v = 0.0f;
            if (n < m) {
                const int j = s_nbr[n];
                v = fmaxf(A[j * HID1 + k] - cik, 0.0f);
            }
            s_h1T[k][n] = v;
        }
    }
    __syncthreads();

    // h2 = h1 @ W2 + b2 (W2 streamed from L1/L2), masked max over n via shuffles
    {
        const int nb = tid & 15, cb = tid >> 4;
        const int n0 = nb * 4, c0 = cb * 8;
        const float* __restrict__ w2p = W2 + c0;

        float acc[4][8];
        #pragma unroll
        for (int nn = 0; nn < 4; ++nn)
            #pragma unroll
            for (int cc = 0; cc < 8; ++cc) acc[nn][cc] = s_b2[c0 + cc];

        #pragma unroll 4
        for (int k = 0; k < HID1; ++k) {
            const float4 h  = *(const float4*)&s_h1T[k][n0];
            const float4 w0 = *(const float4*)(w2p + k * HID2);
            const float4 w1 = *(const float4*)(w2p + k * HID2 + 4);
            const float hv[4] = { h.x, h.y, h.z, h.w };
            const float wv[8] = { w0.x, w0.y, w0.z, w0.w, w1.x, w1.y, w1.z, w1.w };
            #pragma unroll
            for (int nn = 0; nn < 4; ++nn)
                #pragma unroll
                for (int cc = 0; cc < 8; ++cc)
                    acc[nn][cc] = fmaf(hv[nn], wv[cc], acc[nn][cc]);
        }

        float r[8];
        #pragma unroll
        for (int cc = 0; cc < 8; ++cc) {
            float v = -FLT_MAX;
            #pragma unroll
            for (int nn = 0; nn < 4; ++nn)
                if (n0 + nn < m) v = fmaxf(v, acc[nn][cc]);
            r[cc] = v;
        }
        #pragma unroll
        for (int s = 1; s < 16; s <<= 1)
            #pragma unroll
            for (int cc = 0; cc < 8; ++cc)
                r[cc] = fmaxf(r[cc], __shfl_xor(r[cc], s));

        if (nb == 0)
            #pragma unroll
            for (int cc = 0; cc < 8; ++cc)
                out[(size_t)i * HID2 + c0 + cc] = fmaxf(r[cc], 0.0f);
    }
}

extern "C" void kernel_launch(void* const* d_in, const int* in_sizes, int n_in,
                              void* d_out, int out_size, void* d_ws, size_t ws_size,
                              hipStream_t stream) {
    const float* x     = (const float*)d_in[0];
    const float* pos   = (const float*)d_in[1];
    const int*   batch = (const int*)d_in[2];
    const float* W1    = (const float*)d_in[3];
    const float* b1    = (const float*)d_in[4];
    const float* W2    = (const float*)d_in[5];
    const float* b2    = (const float*)d_in[6];
    float* out = (float*)d_out;

    float* A  = (float*)d_ws;                    // NPTS*64
    float* C  = A  + (size_t)NPTS * HID1;        // NPTS*64
    float* SQ = C  + (size_t)NPTS * HID1;        // NPTS

    hipLaunchKernelGGL(prep_kernel, dim3(NPTS * HID1 / 256), dim3(256), 0, stream,
                       x, pos, batch, W1, b1, A, C, SQ, out);
    hipLaunchKernelGGL(pointconv_kernel, dim3(NPTS), dim3(256), 0, stream,
                       pos, batch, W2, b2, A, C, SQ, out);
}

// Round 4
// 102.475 us; speedup vs baseline: 2.6455x; 1.6783x over previous
//
#include <hip/hip_runtime.h>
#include <hip/hip_bf16.h>
#include <float.h>
#include <stdint.h>

#define NPTS 8192
#define SEG  2048
#define CF   16
#define HID1 64
#define HID2 128
#define KMAX 64
#define R2   0.49f
#define CAND_CAP 1024

typedef unsigned long long ULL;
typedef short bf16x8 __attribute__((ext_vector_type(8)));
typedef float f32x4  __attribute__((ext_vector_type(4)));

__device__ __forceinline__ uint32_t f2ord(float f) {
    uint32_t u = __float_as_uint(f);
    return (u & 0x80000000u) ? ~u : (u | 0x80000000u);
}

// round-to-nearest-even f32 -> bf16 bits (values are finite; no NaN path needed)
__device__ __forceinline__ unsigned short f2bf(float f) {
    uint32_t u = __float_as_uint(f);
    return (unsigned short)((u + 0x7fffu + ((u >> 16) & 1u)) >> 16);
}

// ---- prep: A = x@W1[:16] + pos@W1[16:19] + b1 ; C = pos@W1[16:19] ; sq ;
//      W2T[c][k] = bf16(W2[k][c]) ; echo pos/batch ----
__global__ __launch_bounds__(256) void prep_kernel(
    const float* __restrict__ x, const float* __restrict__ pos,
    const int* __restrict__ batch,
    const float* __restrict__ W1, const float* __restrict__ b1,
    const float* __restrict__ W2,
    float* __restrict__ A, float* __restrict__ C, float* __restrict__ sq,
    unsigned short* __restrict__ W2T,
    float* __restrict__ out)
{
    const int t = blockIdx.x * 256 + threadIdx.x;   // t < NPTS*64
    const int i = t >> 6, k = t & 63;

    const float px = pos[3 * i + 0], py = pos[3 * i + 1], pz = pos[3 * i + 2];
    float c = __fmul_rn(px, W1[16 * HID1 + k]);
    c = fmaf(py, W1[17 * HID1 + k], c);
    c = fmaf(pz, W1[18 * HID1 + k], c);

    float a = b1[k];
    #pragma unroll
    for (int cc = 0; cc < CF; ++cc)
        a = fmaf(x[i * CF + cc], W1[cc * HID1 + k], a);
    a += c;

    A[t] = a;
    C[t] = c;

    if (t < HID1 * HID2) {
        // W2T[c][k], row-major c-stride 64
        const int cc = t >> 6, kk = t & 63;
        W2T[t] = f2bf(W2[kk * HID2 + cc]);
    }

    if (k == 0) {
        sq[i] = __fadd_rn(__fadd_rn(__fmul_rn(px, px), __fmul_rn(py, py)),
                          __fmul_rn(pz, pz));
    }
    if (k < 3) out[NPTS * HID2 + 3 * i + k] = pos[3 * i + k];
    if (k == 3) out[NPTS * HID2 + NPTS * 3 + i] = (float)batch[i];
}

// ---- fused: radius scan -> exact top-K -> h1 bf16 in LDS -> MFMA h2 -> max ----
__global__ __launch_bounds__(256, 4) void pointconv_kernel(
    const float* __restrict__ pos, const int* __restrict__ batch,
    const unsigned short* __restrict__ W2T, const float* __restrict__ b2,
    const float* __restrict__ A, const float* __restrict__ C,
    const float* __restrict__ sq, float* __restrict__ out)
{
    __shared__ ULL   s_key[CAND_CAP];                 // 8 KB
    __shared__ __align__(16) unsigned short s_h1[HID1 * HID1]; // 8 KB bf16, swizzled
    __shared__ float s_red[4][HID2];                  // 2 KB
    __shared__ int   s_nbr[KMAX];
    __shared__ int   s_cnt;

    const int tid = threadIdx.x;
    const int i   = blockIdx.x;

    if (tid == 0) s_cnt = 0;

    const int   seg0 = batch[i] * SEG;
    const float pix = pos[3 * i + 0], piy = pos[3 * i + 1], piz = pos[3 * i + 2];
    const float sqi = sq[i];
    __syncthreads();

    // candidate scan, exact reference arithmetic: d2 = (sq_i+sq_j) - 2*dot
    for (int jj = tid; jj < SEG; jj += 256) {
        const int j = seg0 + jj;
        const float pjx = pos[3 * j + 0], pjy = pos[3 * j + 1], pjz = pos[3 * j + 2];
        const float dot = fmaf(piz, pjz, fmaf(piy, pjy, __fmul_rn(pix, pjx)));
        const float d2  = __fsub_rn(__fadd_rn(sqi, sq[j]), __fmul_rn(2.0f, dot));
        if (d2 <= R2) {
            int p = atomicAdd(&s_cnt, 1);
            if (p < CAND_CAP)
                s_key[p] = ((ULL)f2ord(d2) << 32) | (unsigned)j;
        }
    }
    __syncthreads();

    int cnt = s_cnt; if (cnt > CAND_CAP) cnt = CAND_CAP;
    const int m = cnt < KMAX ? cnt : KMAX;

    if (cnt > KMAX) {
        int np2 = 1; while (np2 < cnt) np2 <<= 1;
        for (int e = cnt + tid; e < np2; e += 256) s_key[e] = ~0ULL;
        __syncthreads();
        for (int k = 2; k <= np2; k <<= 1) {
            for (int j = k >> 1; j > 0; j >>= 1) {
                for (int e = tid; e < np2; e += 256) {
                    const int l = e ^ j;
                    if (l > e) {
                        const ULL a = s_key[e], b = s_key[l];
                        const bool asc = ((e & k) == 0);
                        if ((a > b) == asc) { s_key[e] = b; s_key[l] = a; }
                    }
                }
                __syncthreads();
            }
        }
    }
    if (tid < KMAX) s_nbr[tid] = (tid < m) ? (int)(s_key[tid] & 0xffffffffu) : -1;
    __syncthreads();

    // h1[n][k] = relu(A[j_n][k] - C[i][k]) -> bf16 LDS, chunk-XOR swizzled:
    //   s_h1[n*64 + ((k>>3)^(n&7))*8 + (k&7)]
    {
        const int k = tid & 63, w = tid >> 6;
        const float cik = C[i * HID1 + k];
        const int koff = ((k >> 3)) * 8 + (k & 7); // pre-swizzle base (XOR applied per n)
        #pragma unroll
        for (int p = 0; p < 16; ++p) {
            const int n = p * 4 + w;
            float v = 0.0f;
            if (n < m) {
                const int j = s_nbr[n];
                v = fmaxf(A[j * HID1 + k] - cik, 0.0f);
            }
            const int sw = (((k >> 3) ^ (n & 7)) << 3) | (k & 7);
            s_h1[n * HID1 + sw] = f2bf(v);
            (void)koff;
        }
    }
    __syncthreads();

    // h2 via MFMA: per wave w -> rows 16w..16w+15, all 8 col-tiles.
    {
        const int w = tid >> 6, l = tid & 63;
        const int r = l & 15, q = l >> 4;
        const int row = 16 * w + r;

        bf16x8 afrag[2];
        #pragma unroll
        for (int kc = 0; kc < 2; ++kc) {
            const int c8 = (kc * 4 + q) ^ (r & 7);   // row&7 == r&7 (16w ≡ 0 mod 8)
            afrag[kc] = *(const bf16x8*)&s_h1[row * HID1 + c8 * 8];
        }

        f32x4 acc[8];
        #pragma unroll
        for (int cb = 0; cb < 8; ++cb) acc[cb] = (f32x4){0.f, 0.f, 0.f, 0.f};

        #pragma unroll
        for (int cb = 0; cb < 8; ++cb) {
            #pragma unroll
            for (int kc = 0; kc < 2; ++kc) {
                const bf16x8 bfrag =
                    *(const bf16x8*)&W2T[(cb * 16 + r) * HID1 + (kc * 4 + q) * 8];
                acc[cb] = __builtin_amdgcn_mfma_f32_16x16x32_bf16(
                    afrag[kc], bfrag, acc[cb], 0, 0, 0);
            }
        }

        // masked max over this wave's 16 rows; D: col=l&15, row=(l>>4)*4+reg
        const int nbase = 16 * w + q * 4;
        #pragma unroll
        for (int cb = 0; cb < 8; ++cb) {
            float v = -FLT_MAX;
            #pragma unroll
            for (int reg = 0; reg < 4; ++reg)
                if (nbase + reg < m) v = fmaxf(v, acc[cb][reg]);
            v = fmaxf(v, __shfl_xor(v, 16));
            v = fmaxf(v, __shfl_xor(v, 32));
            if (q == 0) s_red[w][cb * 16 + r] = v;
        }
    }
    __syncthreads();

    if (tid < HID2) {
        float v = s_red[0][tid];
        v = fmaxf(v, s_red[1][tid]);
        v = fmaxf(v, s_red[2][tid]);
        v = fmaxf(v, s_red[3][tid]);
        out[(size_t)i * HID2 + tid] = fmaxf(v + b2[tid], 0.0f);
    }
}

extern "C" void kernel_launch(void* const* d_in, const int* in_sizes, int n_in,
                              void* d_out, int out_size, void* d_ws, size_t ws_size,
                              hipStream_t stream) {
    const float* x     = (const float*)d_in[0];
    const float* pos   = (const float*)d_in[1];
    const int*   batch = (const int*)d_in[2];
    const float* W1    = (const float*)d_in[3];
    const float* b1    = (const float*)d_in[4];
    const float* W2    = (const float*)d_in[5];
    const float* b2    = (const float*)d_in[6];
    float* out = (float*)d_out;

    float* A  = (float*)d_ws;                          // NPTS*64 f32
    float* C  = A  + (size_t)NPTS * HID1;              // NPTS*64 f32
    float* SQ = C  + (size_t)NPTS * HID1;              // NPTS f32
    unsigned short* W2T = (unsigned short*)(SQ + NPTS);// 128*64 bf16

    hipLaunchKernelGGL(prep_kernel, dim3(NPTS * HID1 / 256), dim3(256), 0, stream,
                       x, pos, batch, W1, b1, W2, A, C, SQ, W2T, out);
    hipLaunchKernelGGL(pointconv_kernel, dim3(NPTS), dim3(256), 0, stream,
                       pos, batch, W2T, b2, A, C, SQ, out);
}

// Round 5
// 75.943 us; speedup vs baseline: 3.5698x; 1.3494x over previous
//
#include <hip/hip_runtime.h>
#include <hip/hip_bf16.h>
#include <float.h>
#include <stdint.h>

#define NPTS 8192
#define SEG  2048
#define CF   16
#define HID1 64
#define HID2 128
#define KMAX 64
#define R2   0.49f
#define CAP  1024

typedef unsigned long long ULL;
typedef short bf16x8 __attribute__((ext_vector_type(8)));
typedef float f32x4  __attribute__((ext_vector_type(4)));

__device__ __forceinline__ uint32_t f2ord(float f) {
    uint32_t u = __float_as_uint(f);
    return (u & 0x80000000u) ? ~u : (u | 0x80000000u);
}

// RNE f32 -> bf16 bits (finite values)
__device__ __forceinline__ unsigned short f2bf(float f) {
    uint32_t u = __float_as_uint(f);
    return (unsigned short)((u + 0x7fffu + ((u >> 16) & 1u)) >> 16);
}

// ---- prep: A = x@W1[:16] + pos@W1[16:19] + b1 ; C = pos@W1[16:19] ;
//      pos4 = (x,y,z,sq) ; W2T[c][k] = bf16(W2[k][c]) ; echo pos/batch ----
__global__ __launch_bounds__(256) void prep_kernel(
    const float* __restrict__ x, const float* __restrict__ pos,
    const int* __restrict__ batch,
    const float* __restrict__ W1, const float* __restrict__ b1,
    const float* __restrict__ W2,
    float* __restrict__ A, float* __restrict__ C,
    float4* __restrict__ pos4, unsigned short* __restrict__ W2T,
    float* __restrict__ out)
{
    const int t = blockIdx.x * 256 + threadIdx.x;   // t < NPTS*64
    const int i = t >> 6, k = t & 63;

    const float px = pos[3 * i + 0], py = pos[3 * i + 1], pz = pos[3 * i + 2];
    float c = __fmul_rn(px, W1[16 * HID1 + k]);
    c = fmaf(py, W1[17 * HID1 + k], c);
    c = fmaf(pz, W1[18 * HID1 + k], c);

    float a = b1[k];
    #pragma unroll
    for (int cc = 0; cc < CF; ++cc)
        a = fmaf(x[i * CF + cc], W1[cc * HID1 + k], a);
    a += c;

    A[t] = a;
    C[t] = c;

    if (t < HID1 * HID2) {
        const int cc = t >> 6, kk = t & 63;      // W2T[c][k], c-stride 64
        W2T[t] = f2bf(W2[kk * HID2 + cc]);
    }

    if (k == 0) {
        const float sq = __fadd_rn(__fadd_rn(__fmul_rn(px, px), __fmul_rn(py, py)),
                                   __fmul_rn(pz, pz));
        pos4[i] = make_float4(px, py, pz, sq);
    }
    if (k < 3) out[NPTS * HID2 + 3 * i + k] = pos[3 * i + k];
    if (k == 3) out[NPTS * HID2 + NPTS * 3 + i] = (float)batch[i];
}

// ---- 4 centroids/block, 1 wave/centroid: scan -> wave-local top-K sort
//      (no barriers) -> A-frag direct-from-global -> MFMA h2 -> max ----
__global__ __launch_bounds__(256, 4) void pointconv_kernel(
    const int* __restrict__ batch,
    const unsigned short* __restrict__ W2T, const float* __restrict__ b2,
    const float* __restrict__ A, const float* __restrict__ C,
    const float4* __restrict__ pos4, float* __restrict__ out)
{
    __shared__ ULL s_key[4][CAP];   // 32 KB
    __shared__ int s_nbr[4][KMAX];  // 1 KB
    __shared__ int s_cnt[4];

    const int tid = threadIdx.x;
    const int i0  = blockIdx.x * 4;            // 4 centroids, same segment (2048%4==0)
    const int w   = tid >> 6, l = tid & 63;

    if (tid < 4) s_cnt[tid] = 0;

    const float4 cp0 = pos4[i0 + 0], cp1 = pos4[i0 + 1],
                 cp2 = pos4[i0 + 2], cp3 = pos4[i0 + 3];
    const int seg0 = batch[i0] * SEG;
    __syncthreads();

    // scan: each point loaded once (dwordx4), tested vs all 4 centroids
    for (int jj = tid; jj < SEG; jj += 256) {
        const int j = seg0 + jj;
        const float4 pj = pos4[j];
        #pragma unroll
        for (int g = 0; g < 4; ++g) {
            const float4 cg = (g == 0) ? cp0 : (g == 1) ? cp1 : (g == 2) ? cp2 : cp3;
            const float dot = fmaf(cg.z, pj.z, fmaf(cg.y, pj.y, __fmul_rn(cg.x, pj.x)));
            const float d2  = __fsub_rn(__fadd_rn(cg.w, pj.w), __fmul_rn(2.0f, dot));
            if (d2 <= R2) {
                int p = atomicAdd(&s_cnt[g], 1);
                if (p < CAP)
                    s_key[g][p] = ((ULL)f2ord(d2) << 32) | (unsigned)j;
            }
        }
    }
    __syncthreads();   // last block-wide barrier; everything below is wave-local

    int cnt = s_cnt[w]; if (cnt > CAP) cnt = CAP;
    const int m = cnt < KMAX ? cnt : KMAX;
    const int iw = i0 + w;

    if (cnt > KMAX) {
        // per-wave bitonic sort: same-wave DS ops are ordered, no barriers
        int np2 = 1; while (np2 < cnt) np2 <<= 1;
        for (int e = cnt + l; e < np2; e += 64) s_key[w][e] = ~0ULL;
        for (int ks = 2; ks <= np2; ks <<= 1) {
            for (int js = ks >> 1; js > 0; js >>= 1) {
                for (int e = l; e < np2; e += 64) {
                    const int pr = e ^ js;
                    if (pr > e) {
                        const ULL a = s_key[w][e], b = s_key[w][pr];
                        const bool asc = ((e & ks) == 0);
                        if ((a > b) == asc) { s_key[w][e] = b; s_key[w][pr] = a; }
                    }
                }
            }
        }
    }
    if (l < KMAX)
        s_nbr[w][l] = (l < m) ? (int)(s_key[w][l] & 0xffffffffu) : iw;

    // ---- h2 via MFMA; A-fragments gathered straight from A (no LDS) ----
    const int r = l & 15, q = l >> 4;

    // C-vector for this lane's k-slice: k = kc*32 + q*8 + 0..7
    float cv[2][8];
    {
        const float4* Cv = (const float4*)(C + (size_t)iw * HID1);
        #pragma unroll
        for (int kc = 0; kc < 2; ++kc) {
            const float4 c0 = Cv[kc * 8 + q * 2], c1 = Cv[kc * 8 + q * 2 + 1];
            cv[kc][0] = c0.x; cv[kc][1] = c0.y; cv[kc][2] = c0.z; cv[kc][3] = c0.w;
            cv[kc][4] = c1.x; cv[kc][5] = c1.y; cv[kc][6] = c1.z; cv[kc][7] = c1.w;
        }
    }

    bf16x8 af[4][2];
    #pragma unroll
    for (int t = 0; t < 4; ++t) {
        const int row = t * 16 + r;
        const int j = s_nbr[w][row];           // valid index even for row >= m
        const float4* Aj = (const float4*)(A + (size_t)j * HID1);
        #pragma unroll
        for (int kc = 0; kc < 2; ++kc) {
            const float4 a0 = Aj[kc * 8 + q * 2], a1 = Aj[kc * 8 + q * 2 + 1];
            bf16x8 v;
            v[0] = (short)f2bf(fmaxf(a0.x - cv[kc][0], 0.0f));
            v[1] = (short)f2bf(fmaxf(a0.y - cv[kc][1], 0.0f));
            v[2] = (short)f2bf(fmaxf(a0.z - cv[kc][2], 0.0f));
            v[3] = (short)f2bf(fmaxf(a0.w - cv[kc][3], 0.0f));
            v[4] = (short)f2bf(fmaxf(a1.x - cv[kc][4], 0.0f));
            v[5] = (short)f2bf(fmaxf(a1.y - cv[kc][5], 0.0f));
            v[6] = (short)f2bf(fmaxf(a1.z - cv[kc][6], 0.0f));
            v[7] = (short)f2bf(fmaxf(a1.w - cv[kc][7], 0.0f));
            af[t][kc] = v;
        }
    }

    // col-tiles in 4 groups of 2 to bound live accumulators (VGPR <= ~128)
    #pragma unroll
    for (int cbg = 0; cbg < 4; ++cbg) {
        f32x4 acc[4][2];
        #pragma unroll
        for (int t = 0; t < 4; ++t) {
            acc[t][0] = (f32x4){0.f, 0.f, 0.f, 0.f};
            acc[t][1] = (f32x4){0.f, 0.f, 0.f, 0.f};
        }
        #pragma unroll
        for (int cb2 = 0; cb2 < 2; ++cb2) {
            const int cb = cbg * 2 + cb2;
            #pragma unroll
            for (int kc = 0; kc < 2; ++kc) {
                const bf16x8 bf =
                    *(const bf16x8*)&W2T[(cb * 16 + r) * HID1 + kc * 32 + q * 8];
                #pragma unroll
                for (int t = 0; t < 4; ++t)
                    acc[t][cb2] = __builtin_amdgcn_mfma_f32_16x16x32_bf16(
                        af[t][kc], bf, acc[t][cb2], 0, 0, 0);
            }
        }
        #pragma unroll
        for (int cb2 = 0; cb2 < 2; ++cb2) {
            const int c = (cbg * 2 + cb2) * 16 + r;
            float v = -FLT_MAX;
            #pragma unroll
            for (int t = 0; t < 4; ++t) {
                const int nb = t * 16 + q * 4;   // D: col=l&15, row=(l>>4)*4+reg
                #pragma unroll
                for (int reg = 0; reg < 4; ++reg)
                    if (nb + reg < m) v = fmaxf(v, acc[t][cb2][reg]);
            }
            v = fmaxf(v, __shfl_xor(v, 16));
            v = fmaxf(v, __shfl_xor(v, 32));
            if (q == 0)
                out[(size_t)iw * HID2 + c] = fmaxf(v + b2[c], 0.0f);
        }
    }
}

extern "C" void kernel_launch(void* const* d_in, const int* in_sizes, int n_in,
                              void* d_out, int out_size, void* d_ws, size_t ws_size,
                              hipStream_t stream) {
    const float* x     = (const float*)d_in[0];
    const float* pos   = (const float*)d_in[1];
    const int*   batch = (const int*)d_in[2];
    const float* W1    = (const float*)d_in[3];
    const float* b1    = (const float*)d_in[4];
    const float* W2    = (const float*)d_in[5];
    const float* b2    = (const float*)d_in[6];
    float* out = (float*)d_out;

    float*  A    = (float*)d_ws;                          // 2 MB
    float*  C    = A + (size_t)NPTS * HID1;               // 2 MB
    float4* P4   = (float4*)(C + (size_t)NPTS * HID1);    // 128 KB (16B aligned)
    unsigned short* W2T = (unsigned short*)(P4 + NPTS);   // 16 KB

    hipLaunchKernelGGL(prep_kernel, dim3(NPTS * HID1 / 256), dim3(256), 0, stream,
                       x, pos, batch, W1, b1, W2, A, C, P4, W2T, out);
    hipLaunchKernelGGL(pointconv_kernel, dim3(NPTS / 4), dim3(256), 0, stream,
                       batch, W2T, b2, A, C, P4, out);
}

// Round 6
// 74.117 us; speedup vs baseline: 3.6577x; 1.0246x over previous
//
#include <hip/hip_runtime.h>
#include <hip/hip_bf16.h>
#include <float.h>
#include <stdint.h>

#define NPTS 8192
#define SEG  2048
#define CF   16
#define HID1 64
#define HID2 128
#define KMAX 64
#define R2   0.49f
#define CAP  1024

typedef unsigned long long ULL;
typedef short bf16x8 __attribute__((ext_vector_type(8)));
typedef float f32x4  __attribute__((ext_vector_type(4)));

__device__ __forceinline__ uint32_t f2ord(float f) {
    uint32_t u = __float_as_uint(f);
    return (u & 0x80000000u) ? ~u : (u | 0x80000000u);
}

// RNE f32 -> bf16 bits (finite values)
__device__ __forceinline__ unsigned short f2bf(float f) {
    uint32_t u = __float_as_uint(f);
    return (unsigned short)((u + 0x7fffu + ((u >> 16) & 1u)) >> 16);
}

// ---- prep: A = x@W1[:16] + pos@W1[16:19] + b1 ; C = pos@W1[16:19] ;
//      pos4 = (x,y,z,sq) ; W2T[c][k] = bf16(W2[k][c]) ; echo pos/batch ----
__global__ __launch_bounds__(256) void prep_kernel(
    const float* __restrict__ x, const float* __restrict__ pos,
    const int* __restrict__ batch,
    const float* __restrict__ W1, const float* __restrict__ b1,
    const float* __restrict__ W2,
    float* __restrict__ A, float* __restrict__ C,
    float4* __restrict__ pos4, unsigned short* __restrict__ W2T,
    float* __restrict__ out)
{
    const int t = blockIdx.x * 256 + threadIdx.x;   // t < NPTS*64
    const int i = t >> 6, k = t & 63;

    const float px = pos[3 * i + 0], py = pos[3 * i + 1], pz = pos[3 * i + 2];
    float c = __fmul_rn(px, W1[16 * HID1 + k]);
    c = fmaf(py, W1[17 * HID1 + k], c);
    c = fmaf(pz, W1[18 * HID1 + k], c);

    float a = b1[k];
    #pragma unroll
    for (int cc = 0; cc < CF; ++cc)
        a = fmaf(x[i * CF + cc], W1[cc * HID1 + k], a);
    a += c;

    A[t] = a;
    C[t] = c;

    if (t < HID1 * HID2) {
        const int cc = t >> 6, kk = t & 63;      // W2T[c][k], c-stride 64
        W2T[t] = f2bf(W2[kk * HID2 + cc]);
    }

    if (k == 0) {
        const float sq = __fadd_rn(__fadd_rn(__fmul_rn(px, px), __fmul_rn(py, py)),
                                   __fmul_rn(pz, pz));
        pos4[i] = make_float4(px, py, pz, sq);
    }
    if (k < 3) out[NPTS * HID2 + 3 * i + k] = pos[3 * i + k];
    if (k == 3) out[NPTS * HID2 + NPTS * 3 + i] = (float)batch[i];
}

// ---- 4 centroids/block, 1 wave/centroid: scan -> register threshold-select
//      top-K (no sort, no barriers) -> MFMA h2 -> max ----
__global__ __launch_bounds__(256, 4) void pointconv_kernel(
    const int* __restrict__ batch,
    const unsigned short* __restrict__ W2T, const float* __restrict__ b2,
    const float* __restrict__ A, const float* __restrict__ C,
    const float4* __restrict__ pos4, float* __restrict__ out)
{
    __shared__ ULL s_key[4][CAP];   // 32 KB
    __shared__ int s_nbr[4][KMAX];  // 1 KB
    __shared__ int s_cnt[4];
    __shared__ int s_sel[4];

    const int tid = threadIdx.x;
    const int i0  = blockIdx.x * 4;            // 4 centroids, same segment (2048%4==0)
    const int w   = tid >> 6, l = tid & 63;

    if (tid < 4) { s_cnt[tid] = 0; s_sel[tid] = 0; }

    const float4 cp0 = pos4[i0 + 0], cp1 = pos4[i0 + 1],
                 cp2 = pos4[i0 + 2], cp3 = pos4[i0 + 3];
    const int seg0 = batch[i0] * SEG;
    __syncthreads();

    // scan: each point loaded once (dwordx4), tested vs all 4 centroids
    for (int jj = tid; jj < SEG; jj += 256) {
        const int j = seg0 + jj;
        const float4 pj = pos4[j];
        #pragma unroll
        for (int g = 0; g < 4; ++g) {
            const float4 cg = (g == 0) ? cp0 : (g == 1) ? cp1 : (g == 2) ? cp2 : cp3;
            const float dot = fmaf(cg.z, pj.z, fmaf(cg.y, pj.y, __fmul_rn(cg.x, pj.x)));
            const float d2  = __fsub_rn(__fadd_rn(cg.w, pj.w), __fmul_rn(2.0f, dot));
            if (d2 <= R2) {
                int p = atomicAdd(&s_cnt[g], 1);
                if (p < CAP)
                    s_key[g][p] = ((ULL)f2ord(d2) << 32) | (unsigned)j;
            }
        }
    }
    __syncthreads();   // last block-wide barrier; everything below is wave-local

    int cnt = s_cnt[w]; if (cnt > CAP) cnt = CAP;
    const int m = cnt < KMAX ? cnt : KMAX;
    const int iw = i0 + w;

    if (cnt <= KMAX) {
        if (l < KMAX)
            s_nbr[w][l] = (l < m) ? (int)(s_key[w][l] & 0xffffffffu) : iw;
    } else {
        // load my candidates into registers (static indices only)
        uint32_t eo[16], ej[16];
        #pragma unroll
        for (int g = 0; g < 16; ++g) {
            eo[g] = 0xffffffffu; ej[g] = 0xffffffffu;
            if (64 * g < cnt) {                       // wave-uniform chunk guard
                const int e = l + 64 * g;
                if (e < cnt) {
                    const ULL kk = s_key[w][e];
                    eo[g] = (uint32_t)(kk >> 32);
                    ej[g] = (uint32_t)(kk & 0xffffffffu);
                }
            }
        }
        // binary search: smallest T with count(ord <= T) >= 64.
        // d2 may be slightly negative (self), so lo = 0; d2 <= R2 -> ord <= ord(R2).
        uint32_t lo = 0u, hi = 0x80000000u | __float_as_uint(R2);
        while (lo < hi) {
            const uint32_t mid = lo + ((hi - lo) >> 1);
            int c = 0;
            #pragma unroll
            for (int g = 0; g < 16; ++g)
                if (64 * g < cnt) c += (eo[g] <= mid) ? 1 : 0;
            #pragma unroll
            for (int s = 1; s < 64; s <<= 1) c += __shfl_xor(c, s);
            if (c >= KMAX) hi = mid; else lo = mid + 1;
        }
        const uint32_t T = lo;

        int cLT = 0, cLE = 0;
        #pragma unroll
        for (int g = 0; g < 16; ++g)
            if (64 * g < cnt) { cLT += (eo[g] < T) ? 1 : 0; cLE += (eo[g] <= T) ? 1 : 0; }
        #pragma unroll
        for (int s = 1; s < 64; s <<= 1) { cLT += __shfl_xor(cLT, s); cLE += __shfl_xor(cLE, s); }

        // tie resolution on j (exact: keys unique). Rarely taken (cLE == 64 usually).
        uint32_t J = 0xffffffffu;
        if (cLE > KMAX) {
            const int need = KMAX - cLT;
            uint32_t jlo = 0u, jhi = NPTS - 1;
            while (jlo < jhi) {
                const uint32_t jmid = jlo + ((jhi - jlo) >> 1);
                int c = 0;
                #pragma unroll
                for (int g = 0; g < 16; ++g)
                    if (64 * g < cnt) c += (eo[g] == T && ej[g] <= jmid) ? 1 : 0;
                #pragma unroll
                for (int s = 1; s < 64; s <<= 1) c += __shfl_xor(c, s);
                if (c >= need) jhi = jmid; else jlo = jmid + 1;
            }
            J = jlo;
        }
        // compact selected set into s_nbr (order irrelevant for max-agg)
        #pragma unroll
        for (int g = 0; g < 16; ++g) {
            if (64 * g < cnt) {
                const bool take = (eo[g] < T) || ((eo[g] == T) && (ej[g] <= J));
                if (take) {
                    const int p = atomicAdd(&s_sel[w], 1);
                    s_nbr[w][p] = (int)ej[g];
                }
            }
        }
    }

    // ---- h2 via MFMA; A-fragments gathered straight from A (no LDS) ----
    const int r = l & 15, q = l >> 4;

    // C-vector for this lane's k-slice: k = kc*32 + q*8 + 0..7
    float cv[2][8];
    {
        const float4* Cv = (const float4*)(C + (size_t)iw * HID1);
        #pragma unroll
        for (int kc = 0; kc < 2; ++kc) {
            const float4 c0 = Cv[kc * 8 + q * 2], c1 = Cv[kc * 8 + q * 2 + 1];
            cv[kc][0] = c0.x; cv[kc][1] = c0.y; cv[kc][2] = c0.z; cv[kc][3] = c0.w;
            cv[kc][4] = c1.x; cv[kc][5] = c1.y; cv[kc][6] = c1.z; cv[kc][7] = c1.w;
        }
    }

    bf16x8 af[4][2];
    #pragma unroll
    for (int t = 0; t < 4; ++t) {
        const int row = t * 16 + r;
        const int j = s_nbr[w][row];           // valid index even for row >= m
        const float4* Aj = (const float4*)(A + (size_t)j * HID1);
        #pragma unroll
        for (int kc = 0; kc < 2; ++kc) {
            const float4 a0 = Aj[kc * 8 + q * 2], a1 = Aj[kc * 8 + q * 2 + 1];
            bf16x8 v;
            v[0] = (short)f2bf(fmaxf(a0.x - cv[kc][0], 0.0f));
            v[1] = (short)f2bf(fmaxf(a0.y - cv[kc][1], 0.0f));
            v[2] = (short)f2bf(fmaxf(a0.z - cv[kc][2], 0.0f));
            v[3] = (short)f2bf(fmaxf(a0.w - cv[kc][3], 0.0f));
            v[4] = (short)f2bf(fmaxf(a1.x - cv[kc][4], 0.0f));
            v[5] = (short)f2bf(fmaxf(a1.y - cv[kc][5], 0.0f));
            v[6] = (short)f2bf(fmaxf(a1.z - cv[kc][6], 0.0f));
            v[7] = (short)f2bf(fmaxf(a1.w - cv[kc][7], 0.0f));
            af[t][kc] = v;
        }
    }

    // col-tiles in 4 groups of 2 to bound live accumulators
    #pragma unroll
    for (int cbg = 0; cbg < 4; ++cbg) {
        f32x4 acc[4][2];
        #pragma unroll
        for (int t = 0; t < 4; ++t) {
            acc[t][0] = (f32x4){0.f, 0.f, 0.f, 0.f};
            acc[t][1] = (f32x4){0.f, 0.f, 0.f, 0.f};
        }
        #pragma unroll
        for (int cb2 = 0; cb2 < 2; ++cb2) {
            const int cb = cbg * 2 + cb2;
            #pragma unroll
            for (int kc = 0; kc < 2; ++kc) {
                const bf16x8 bf =
                    *(const bf16x8*)&W2T[(cb * 16 + r) * HID1 + kc * 32 + q * 8];
                #pragma unroll
                for (int t = 0; t < 4; ++t)
                    acc[t][cb2] = __builtin_amdgcn_mfma_f32_16x16x32_bf16(
                        af[t][kc], bf, acc[t][cb2], 0, 0, 0);
            }
        }
        #pragma unroll
        for (int cb2 = 0; cb2 < 2; ++cb2) {
            const int c = (cbg * 2 + cb2) * 16 + r;
            float v = -FLT_MAX;
            #pragma unroll
            for (int t = 0; t < 4; ++t) {
                const int nb = t * 16 + q * 4;   // D: col=l&15, row=(l>>4)*4+reg
                #pragma unroll
                for (int reg = 0; reg < 4; ++reg)
                    if (nb + reg < m) v = fmaxf(v, acc[t][cb2][reg]);
            }
            v = fmaxf(v, __shfl_xor(v, 16));
            v = fmaxf(v, __shfl_xor(v, 32));
            if (q == 0)
                out[(size_t)iw * HID2 + c] = fmaxf(v + b2[c], 0.0f);
        }
    }
}

extern "C" void kernel_launch(void* const* d_in, const int* in_sizes, int n_in,
                              void* d_out, int out_size, void* d_ws, size_t ws_size,
                              hipStream_t stream) {
    const float* x     = (const float*)d_in[0];
    const float* pos   = (const float*)d_in[1];
    const int*   batch = (const int*)d_in[2];
    const float* W1    = (const float*)d_in[3];
    const float* b1    = (const float*)d_in[4];
    const float* W2    = (const float*)d_in[5];
    const float* b2    = (const float*)d_in[6];
    float* out = (float*)d_out;

    float*  A    = (float*)d_ws;                          // 2 MB
    float*  C    = A + (size_t)NPTS * HID1;               // 2 MB
    float4* P4   = (float4*)(C + (size_t)NPTS * HID1);    // 128 KB (16B aligned)
    unsigned short* W2T = (unsigned short*)(P4 + NPTS);   // 16 KB

    hipLaunchKernelGGL(prep_kernel, dim3(NPTS * HID1 / 256), dim3(256), 0, stream,
                       x, pos, batch, W1, b1, W2, A, C, P4, W2T, out);
    hipLaunchKernelGGL(pointconv_kernel, dim3(NPTS / 4), dim3(256), 0, stream,
                       batch, W2T, b2, A, C, P4, out);
}

// Round 7
// 70.518 us; speedup vs baseline: 3.8444x; 1.0510x over previous
//
#include <hip/hip_runtime.h>
#include <hip/hip_bf16.h>
#include <float.h>
#include <stdint.h>

#define NPTS 8192
#define SEG  2048
#define CF   16
#define HID1 64
#define HID2 128
#define KMAX 64
#define R2   0.49f
#define CAP  384          // max in-radius candidates ~170 expected; +16 sigma margin
#define NCH  6            // CAP / 64

typedef unsigned long long ULL;
typedef short bf16x8 __attribute__((ext_vector_type(8)));
typedef float f32x4  __attribute__((ext_vector_type(4)));

__device__ __forceinline__ uint32_t f2ord(float f) {
    uint32_t u = __float_as_uint(f);
    return (u & 0x80000000u) ? ~u : (u | 0x80000000u);
}

// RNE f32 -> bf16 bits (finite values)
__device__ __forceinline__ unsigned short f2bf(float f) {
    uint32_t u = __float_as_uint(f);
    return (unsigned short)((u + 0x7fffu + ((u >> 16) & 1u)) >> 16);
}

// ---- prep: A = x@W1[:16] + pos@W1[16:19] + b1 ; C = pos@W1[16:19] ;
//      pos4 = (x,y,z,sq) ; W2T[c][k] = bf16(W2[k][c]) ; echo pos/batch ----
__global__ __launch_bounds__(256) void prep_kernel(
    const float* __restrict__ x, const float* __restrict__ pos,
    const int* __restrict__ batch,
    const float* __restrict__ W1, const float* __restrict__ b1,
    const float* __restrict__ W2,
    float* __restrict__ A, float* __restrict__ C,
    float4* __restrict__ pos4, unsigned short* __restrict__ W2T,
    float* __restrict__ out)
{
    const int t = blockIdx.x * 256 + threadIdx.x;   // t < NPTS*64
    const int i = t >> 6, k = t & 63;

    const float px = pos[3 * i + 0], py = pos[3 * i + 1], pz = pos[3 * i + 2];
    float c = __fmul_rn(px, W1[16 * HID1 + k]);
    c = fmaf(py, W1[17 * HID1 + k], c);
    c = fmaf(pz, W1[18 * HID1 + k], c);

    float a = b1[k];
    #pragma unroll
    for (int cc = 0; cc < CF; ++cc)
        a = fmaf(x[i * CF + cc], W1[cc * HID1 + k], a);
    a += c;

    A[t] = a;
    C[t] = c;

    if (t < HID1 * HID2) {
        const int cc = t >> 6, kk = t & 63;      // W2T[c][k], c-stride 64
        W2T[t] = f2bf(W2[kk * HID2 + cc]);
    }

    if (k == 0) {
        const float sq = __fadd_rn(__fadd_rn(__fmul_rn(px, px), __fmul_rn(py, py)),
                                   __fmul_rn(pz, pz));
        pos4[i] = make_float4(px, py, pz, sq);
    }
    if (k < 3) out[NPTS * HID2 + 3 * i + k] = pos[3 * i + k];
    if (k == 3) out[NPTS * HID2 + NPTS * 3 + i] = (float)batch[i];
}

// ---- 1 wave = 1 centroid, fully independent: ballot-compacted scan ->
//      register threshold-select top-K -> MFMA h2 -> max. NO barriers/atomics ----
__global__ __launch_bounds__(256, 4) void pointconv_kernel(
    const int* __restrict__ batch,
    const unsigned short* __restrict__ W2T, const float* __restrict__ b2,
    const float* __restrict__ A, const float* __restrict__ C,
    const float4* __restrict__ pos4, float* __restrict__ out)
{
    __shared__ ULL s_key[4][CAP];   // 12 KB
    __shared__ int s_nbr[4][KMAX];  // 1 KB

    const int tid = threadIdx.x;
    const int w   = tid >> 6, l = tid & 63;
    const int iw  = blockIdx.x * 4 + w;

    const float4 cw = pos4[iw];
    const int seg0 = batch[iw] * SEG;
    ULL* __restrict__ key = &s_key[w][0];

    // wave-private scan with ballot compaction (no atomics)
    int cnt = 0;
    #pragma unroll 4
    for (int it = 0; it < SEG / 64; ++it) {
        const int j = seg0 + it * 64 + l;
        const float4 pj = pos4[j];
        const float dot = fmaf(cw.z, pj.z, fmaf(cw.y, pj.y, __fmul_rn(cw.x, pj.x)));
        const float d2  = __fsub_rn(__fadd_rn(cw.w, pj.w), __fmul_rn(2.0f, dot));
        const bool hit = (d2 <= R2);
        const ULL mask = __ballot(hit);
        if (hit) {
            const int p = cnt + __popcll(mask & ((1ull << l) - 1ull));
            if (p < CAP)
                key[p] = ((ULL)f2ord(d2) << 32) | (unsigned)j;
        }
        cnt += __popcll(mask);
    }
    if (cnt > CAP) cnt = CAP;
    const int m = cnt < KMAX ? cnt : KMAX;

    if (cnt <= KMAX) {
        if (l < KMAX)
            s_nbr[w][l] = (l < m) ? (int)(key[l] & 0xffffffffu) : iw;
    } else {
        // register-resident exact threshold select (top-K set == lax.top_k set)
        uint32_t eo[NCH], ej[NCH];
        #pragma unroll
        for (int g = 0; g < NCH; ++g) {
            eo[g] = 0xffffffffu; ej[g] = 0xffffffffu;
            if (64 * g < cnt) {
                const int e = l + 64 * g;
                if (e < cnt) {
                    const ULL kk = key[e];
                    eo[g] = (uint32_t)(kk >> 32);
                    ej[g] = (uint32_t)(kk & 0xffffffffu);
                }
            }
        }
        // smallest T with count(ord <= T) >= 64
        uint32_t lo = 0u, hi = 0x80000000u | __float_as_uint(R2);
        while (lo < hi) {
            const uint32_t mid = lo + ((hi - lo) >> 1);
            int c = 0;
            #pragma unroll
            for (int g = 0; g < NCH; ++g)
                if (64 * g < cnt) c += (eo[g] <= mid) ? 1 : 0;
            #pragma unroll
            for (int s = 1; s < 64; s <<= 1) c += __shfl_xor(c, s);
            if (c >= KMAX) hi = mid; else lo = mid + 1;
        }
        const uint32_t T = lo;

        int cLT = 0, cLE = 0;
        #pragma unroll
        for (int g = 0; g < NCH; ++g)
            if (64 * g < cnt) { cLT += (eo[g] < T) ? 1 : 0; cLE += (eo[g] <= T) ? 1 : 0; }
        #pragma unroll
        for (int s = 1; s < 64; s <<= 1) { cLT += __shfl_xor(cLT, s); cLE += __shfl_xor(cLE, s); }

        // tie resolution on j (exact; rarely taken)
        uint32_t J = 0xffffffffu;
        if (cLE > KMAX) {
            const int need = KMAX - cLT;
            uint32_t jlo = 0u, jhi = NPTS - 1;
            while (jlo < jhi) {
                const uint32_t jmid = jlo + ((jhi - jlo) >> 1);
                int c = 0;
                #pragma unroll
                for (int g = 0; g < NCH; ++g)
                    if (64 * g < cnt) c += (eo[g] == T && ej[g] <= jmid) ? 1 : 0;
                #pragma unroll
                for (int s = 1; s < 64; s <<= 1) c += __shfl_xor(c, s);
                if (c >= need) jhi = jmid; else jlo = jmid + 1;
            }
            J = jlo;
        }
        // ballot-compact the selected 64 into s_nbr (order irrelevant for max-agg)
        int selbase = 0;
        #pragma unroll
        for (int g = 0; g < NCH; ++g) {
            if (64 * g < cnt) {
                const bool take = (eo[g] < T) || ((eo[g] == T) && (ej[g] <= J));
                const ULL mk = __ballot(take);
                if (take)
                    s_nbr[w][selbase + __popcll(mk & ((1ull << l) - 1ull))] = (int)ej[g];
                selbase += __popcll(mk);
            }
        }
    }

    // ---- h2 via MFMA; A-fragments gathered straight from A (no LDS stage) ----
    const int r = l & 15, q = l >> 4;

    // C-vector for this lane's k-slice: k = kc*32 + q*8 + 0..7
    float cv[2][8];
    {
        const float4* Cv = (const float4*)(C + (size_t)iw * HID1);
        #pragma unroll
        for (int kc = 0; kc < 2; ++kc) {
            const float4 c0 = Cv[kc * 8 + q * 2], c1 = Cv[kc * 8 + q * 2 + 1];
            cv[kc][0] = c0.x; cv[kc][1] = c0.y; cv[kc][2] = c0.z; cv[kc][3] = c0.w;
            cv[kc][4] = c1.x; cv[kc][5] = c1.y; cv[kc][6] = c1.z; cv[kc][7] = c1.w;
        }
    }

    bf16x8 af[4][2];
    #pragma unroll
    for (int t = 0; t < 4; ++t) {
        const int row = t * 16 + r;
        const int j = s_nbr[w][row];           // valid index even for row >= m
        const float4* Aj = (const float4*)(A + (size_t)j * HID1);
        #pragma unroll
        for (int kc = 0; kc < 2; ++kc) {
            const float4 a0 = Aj[kc * 8 + q * 2], a1 = Aj[kc * 8 + q * 2 + 1];
            bf16x8 v;
            v[0] = (short)f2bf(fmaxf(a0.x - cv[kc][0], 0.0f));
            v[1] = (short)f2bf(fmaxf(a0.y - cv[kc][1], 0.0f));
            v[2] = (short)f2bf(fmaxf(a0.z - cv[kc][2], 0.0f));
            v[3] = (short)f2bf(fmaxf(a0.w - cv[kc][3], 0.0f));
            v[4] = (short)f2bf(fmaxf(a1.x - cv[kc][4], 0.0f));
            v[5] = (short)f2bf(fmaxf(a1.y - cv[kc][5], 0.0f));
            v[6] = (short)f2bf(fmaxf(a1.z - cv[kc][6], 0.0f));
            v[7] = (short)f2bf(fmaxf(a1.w - cv[kc][7], 0.0f));
            af[t][kc] = v;
        }
    }

    // col-tiles in 4 groups of 2 to bound live accumulators
    #pragma unroll
    for (int cbg = 0; cbg < 4; ++cbg) {
        f32x4 acc[4][2];
        #pragma unroll
        for (int t = 0; t < 4; ++t) {
            acc[t][0] = (f32x4){0.f, 0.f, 0.f, 0.f};
            acc[t][1] = (f32x4){0.f, 0.f, 0.f, 0.f};
        }
        #pragma unroll
        for (int cb2 = 0; cb2 < 2; ++cb2) {
            const int cb = cbg * 2 + cb2;
            #pragma unroll
            for (int kc = 0; kc < 2; ++kc) {
                const bf16x8 bf =
                    *(const bf16x8*)&W2T[(cb * 16 + r) * HID1 + kc * 32 + q * 8];
                #pragma unroll
                for (int t = 0; t < 4; ++t)
                    acc[t][cb2] = __builtin_amdgcn_mfma_f32_16x16x32_bf16(
                        af[t][kc], bf, acc[t][cb2], 0, 0, 0);
            }
        }
        #pragma unroll
        for (int cb2 = 0; cb2 < 2; ++cb2) {
            const int c = (cbg * 2 + cb2) * 16 + r;
            float v = -FLT_MAX;
            #pragma unroll
            for (int t = 0; t < 4; ++t) {
                const int nb = t * 16 + q * 4;   // D: col=l&15, row=(l>>4)*4+reg
                #pragma unroll
                for (int reg = 0; reg < 4; ++reg)
                    if (nb + reg < m) v = fmaxf(v, acc[t][cb2][reg]);
            }
            v = fmaxf(v, __shfl_xor(v, 16));
            v = fmaxf(v, __shfl_xor(v, 32));
            if (q == 0)
                out[(size_t)iw * HID2 + c] = fmaxf(v + b2[c], 0.0f);
        }
    }
}

extern "C" void kernel_launch(void* const* d_in, const int* in_sizes, int n_in,
                              void* d_out, int out_size, void* d_ws, size_t ws_size,
                              hipStream_t stream) {
    const float* x     = (const float*)d_in[0];
    const float* pos   = (const float*)d_in[1];
    const int*   batch = (const int*)d_in[2];
    const float* W1    = (const float*)d_in[3];
    const float* b1    = (const float*)d_in[4];
    const float* W2    = (const float*)d_in[5];
    const float* b2    = (const float*)d_in[6];
    float* out = (float*)d_out;

    float*  A    = (float*)d_ws;                          // 2 MB
    float*  C    = A + (size_t)NPTS * HID1;               // 2 MB
    float4* P4   = (float4*)(C + (size_t)NPTS * HID1);    // 128 KB (16B aligned)
    unsigned short* W2T = (unsigned short*)(P4 + NPTS);   // 16 KB

    hipLaunchKernelGGL(prep_kernel, dim3(NPTS * HID1 / 256), dim3(256), 0, stream,
                       x, pos, batch, W1, b1, W2, A, C, P4, W2T, out);
    hipLaunchKernelGGL(pointconv_kernel, dim3(NPTS / 4), dim3(256), 0, stream,
                       batch, W2T, b2, A, C, P4, out);
}